// Round 1
// baseline (339.846 us; speedup 1.0000x reference)
//
#include <hip/hip_runtime.h>
#include <stdint.h>

#define NTOK 32768
#define BD   512
#define NB   16
#define LYK  256
#define IMGD 768

typedef __attribute__((ext_vector_type(4))) float f32x4;
typedef __attribute__((ext_vector_type(8))) short s16x8;
typedef __attribute__((ext_vector_type(4))) unsigned short u16x4;
typedef unsigned short u16;

__device__ __forceinline__ float bf2f(u16 u) {
  union { uint32_t i; float f; } v; v.i = ((uint32_t)u) << 16; return v.f;
}
__device__ __forceinline__ u16 f2bf(float f) {
  union { float f; uint32_t i; } v; v.f = f;
  uint32_t r = v.i + 0x7fffu + ((v.i >> 16) & 1u);
  return (u16)(r >> 16);
}
__device__ __forceinline__ u16 f2bf_fast(float f) {  // round-half-up, pos inputs
  union { float f; uint32_t i; } v; v.f = f;
  return (u16)((v.i + 0x8000u) >> 16);
}
__device__ __forceinline__ void gl_lds16(const u16* g, u16* l) {
  __builtin_amdgcn_global_load_lds(
      (const __attribute__((address_space(1))) uint32_t*)g,
      (__attribute__((address_space(3))) uint32_t*)l, 16, 0, 0);
}
__device__ __forceinline__ f32x4 mfma16(s16x8 a, s16x8 b, f32x4 c) {
  return __builtin_amdgcn_mfma_f32_16x16x32_bf16(a, b, c, 0, 0, 0);
}
__device__ __forceinline__ uint32_t cvtpk(float a, float b) {
  uint32_t r;
  asm("v_cvt_pk_bf16_f32 %0, %1, %2" : "=v"(r) : "v"(a), "v"(b));
  return r;
}

// ---- prep: fused fp32->bf16 converts + LayerNorm(F) + batch offsets ------
__global__ __launch_bounds__(256) void prep(
    const float* __restrict__ wq, const float* __restrict__ wk,
    const float* __restrict__ wv, const float* __restrict__ wo,
    const float* __restrict__ w2, const float* __restrict__ w1,
    const float* __restrict__ y,  const float* __restrict__ F,
    const float* __restrict__ g,  const float* __restrict__ be,
    const int* __restrict__ bids,
    u16* __restrict__ dq, u16* __restrict__ dkv, u16* __restrict__ dwo,
    u16* __restrict__ dw2, u16* __restrict__ dw1, u16* __restrict__ dy,
    u16* __restrict__ xn, int* __restrict__ off) {
  const int bid = blockIdx.x;
  if (bid < 2368) {
    const float* s; u16* d; int base;
    if      (bid < 128)  { s = wq; d = dq;            base = 0;   }
    else if (bid < 256)  { s = wk; d = dkv;           base = 128; }
    else if (bid < 384)  { s = wv; d = dkv + 262144;  base = 256; }
    else if (bid < 512)  { s = wo; d = dwo;           base = 384; }
    else if (bid < 640)  { s = w2; d = dw2;           base = 512; }
    else if (bid < 832)  { s = w1; d = dw1;           base = 640; }
    else                 { s = y;  d = dy;            base = 832; }
    int i = ((bid - base) * 256 + threadIdx.x) * 8;
    f32x4 a = *(const f32x4*)(s + i);
    f32x4 b = *(const f32x4*)(s + i + 4);
    s16x8 o;
#pragma unroll
    for (int j = 0; j < 4; ++j) { o[j] = (short)f2bf(a[j]); o[4 + j] = (short)f2bf(b[j]); }
    *(s16x8*)(d + i) = o;
  } else if (bid < 10560) {
    const int lane = threadIdx.x & 63;
    const size_t row = (size_t)(bid - 2368) * 4 + (threadIdx.x >> 6);
    const float* x = F + row * BD + lane * 8;
    f32x4 a = *(const f32x4*)x;
    f32x4 b = *(const f32x4*)(x + 4);
    float v[8] = {a[0], a[1], a[2], a[3], b[0], b[1], b[2], b[3]};
    float s = 0.f, s2 = 0.f;
#pragma unroll
    for (int j = 0; j < 8; ++j) { s += v[j]; s2 += v[j] * v[j]; }
#pragma unroll
    for (int m = 1; m < 64; m <<= 1) { s += __shfl_xor(s, m); s2 += __shfl_xor(s2, m); }
    float mean = s * (1.f / BD);
    float rstd = rsqrtf(s2 * (1.f / BD) - mean * mean + 1e-5f);
    const float* gp = g + lane * 8;
    const float* bp = be + lane * 8;
    s16x8 o;
#pragma unroll
    for (int j = 0; j < 8; ++j) o[j] = (short)f2bf((v[j] - mean) * rstd * gp[j] + bp[j]);
    *(s16x8*)(xn + row * BD + lane * 8) = o;
  } else {
    int b = threadIdx.x;
    if (b > NB) return;
    int lo = 0, hi = NTOK;
    while (lo < hi) { int mid = (lo + hi) >> 1; if (bids[mid] < b) lo = mid + 1; else hi = mid; }
    off[b] = lo;
  }
}

// ---------------- LayerNorm: bf16 in -> fp32 out ----------------
__global__ __launch_bounds__(256) void ln_bf16_f32(const u16* __restrict__ Z,
                                                   const float* __restrict__ g,
                                                   const float* __restrict__ be,
                                                   float* __restrict__ out) {
  const int lane = threadIdx.x & 63;
  const size_t row = (size_t)blockIdx.x * 4 + (threadIdx.x >> 6);
  s16x8 zv = *(const s16x8*)(Z + row * BD + lane * 8);
  float v[8];
#pragma unroll
  for (int j = 0; j < 8; ++j) v[j] = bf2f((u16)zv[j]);
  float s = 0.f, s2 = 0.f;
#pragma unroll
  for (int j = 0; j < 8; ++j) { s += v[j]; s2 += v[j] * v[j]; }
#pragma unroll
  for (int m = 1; m < 64; m <<= 1) { s += __shfl_xor(s, m); s2 += __shfl_xor(s2, m); }
  float mean = s * (1.f / BD);
  float rstd = rsqrtf(s2 * (1.f / BD) - mean * mean + 1e-5f);
  const float* gp = g + lane * 8;
  const float* bp = be + lane * 8;
  f32x4 o0, o1;
#pragma unroll
  for (int j = 0; j < 4; ++j) o0[j] = (v[j] - mean) * rstd * gp[j] + bp[j];
#pragma unroll
  for (int j = 0; j < 4; ++j) o1[j] = (v[4 + j] - mean) * rstd * gp[4 + j] + bp[4 + j];
  float* op = out + row * BD + lane * 8;
  *(f32x4*)op = o0;
  *(f32x4*)(op + 4) = o1;
}

// ---------------- TM=64 NT GEMM (small M), BK=32 --------------------------
template <int EPI>
__global__ __launch_bounds__(256, 2) void gemm64(const u16* __restrict__ A,
                                                 const u16* __restrict__ W,
                                                 const float* __restrict__ bias,
                                                 u16* __restrict__ C, int K) {
  __shared__ u16 As[64 * 32];
  __shared__ u16 Bs[128 * 32];
  const int tid = threadIdx.x;
  const int wave = tid >> 6, lane = tid & 63;
  const int wn = wave * 32;
  const int quad = lane >> 4, l16 = lane & 15;
  const int m0 = blockIdx.x * 64, n0 = blockIdx.y * 128;

  f32x4 acc[4][2];
#pragma unroll
  for (int i = 0; i < 4; ++i)
#pragma unroll
    for (int j = 0; j < 2; ++j) acc[i][j] = f32x4{0.f, 0.f, 0.f, 0.f};

  const int scol = (lane & 3) * 8;
  const u16* gA0 = A + (size_t)(m0 + wave * 16 + (lane >> 2)) * K + scol;
  const u16* gW0 = W + (size_t)(n0 + wave * 32 + (lane >> 2)) * K + scol;
  const u16* gW1 = gW0 + (size_t)16 * K;
  u16* lA = As + wave * 512;
  u16* lB = Bs + wave * 1024;

  for (int k0 = 0; k0 < K; k0 += 32) {
    __syncthreads();
    gl_lds16(gA0 + k0, lA);
    gl_lds16(gW0 + k0, lB);
    gl_lds16(gW1 + k0, lB + 512);
    __syncthreads();
    s16x8 af[4], bfr[2];
#pragma unroll
    for (int mt = 0; mt < 4; ++mt)
      af[mt] = *(const s16x8*)&As[(mt * 16 + l16) * 32 + quad * 8];
#pragma unroll
    for (int nt = 0; nt < 2; ++nt)
      bfr[nt] = *(const s16x8*)&Bs[(wn + nt * 16 + l16) * 32 + quad * 8];
#pragma unroll
    for (int mt = 0; mt < 4; ++mt)
#pragma unroll
      for (int nt = 0; nt < 2; ++nt)
        acc[mt][nt] = mfma16(af[mt], bfr[nt], acc[mt][nt]);
  }

#pragma unroll
  for (int nt = 0; nt < 2; ++nt) {
    const int n = n0 + wn + nt * 16 + l16;
    const float bia = bias[n];
#pragma unroll
    for (int mt = 0; mt < 4; ++mt) {
      const int mb = m0 + mt * 16 + quad * 4;
#pragma unroll
      for (int r = 0; r < 4; ++r) {
        float v = acc[mt][nt][r] + bia;
        if (EPI == 1) v = 0.5f * v * (1.f + erff(v * 0.70710678118654752f));
        C[(size_t)(mb + r) * BD + n] = f2bf(v);
      }
    }
  }
}

// ---------------- TM=128 NT GEMM, BK=32, double-buffered ------------------
// One barrier per K-iter: loads for iter k+1 issue after the barrier and
// their vmcnt-drain lands at the NEXT barrier (one MFMA phase of overlap).
// Bank-clean [128][32] layout (row stride 64B -> full-wave conflict-free).
// EPI 0: bf16 out; 2: +resid bf16; 3: dual K/V out, V transposed into C2
template <int EPI, int SWZ>
__global__ __launch_bounds__(256, 2) void gemm128(const u16* __restrict__ A,
                                                  const u16* __restrict__ W,
                                                  const float* __restrict__ bias,
                                                  u16* __restrict__ C,
                                                  const u16* __restrict__ resid,
                                                  u16* __restrict__ C2,
                                                  const float* __restrict__ bias2,
                                                  int K) {
  __shared__ u16 As[2][128 * 32];
  __shared__ u16 Bs[2][128 * 32];
  const int tid = threadIdx.x;
  const int wave = tid >> 6, lane = tid & 63;
  const int wm = (wave & 1) * 64, wn = (wave >> 1) * 64;
  const int quad = lane >> 4, l16 = lane & 15;
  int m_t, n_t;
  if (SWZ) {  // bid&7 = XCD slot; N-blocks sharing an A-tile on one XCD
    const int bid = blockIdx.x;
    const int xcd = bid & 7, j = bid >> 3;
    n_t = j & 3;
    m_t = xcd + (j >> 2) * 8;
  } else {
    m_t = blockIdx.x; n_t = blockIdx.y;
  }
  const int m0 = m_t * 128, n0 = n_t * 128;

  f32x4 acc[4][4];
#pragma unroll
  for (int i = 0; i < 4; ++i)
#pragma unroll
    for (int j = 0; j < 4; ++j) acc[i][j] = f32x4{0.f, 0.f, 0.f, 0.f};

  const int srow = wave * 32 + (lane >> 2);
  const int scol = (lane & 3) * 8;
  const u16* gA0 = A + (size_t)(m0 + srow) * K + scol;
  const u16* gA1 = gA0 + (size_t)16 * K;
  const u16* gW0 = W + (size_t)(n0 + srow) * K + scol;
  const u16* gW1 = gW0 + (size_t)16 * K;
  const int wb = wave * 1024;

  // prologue: fill buffer 0
  gl_lds16(gA0, &As[0][wb]);
  gl_lds16(gA1, &As[0][wb + 512]);
  gl_lds16(gW0, &Bs[0][wb]);
  gl_lds16(gW1, &Bs[0][wb + 512]);

  int buf = 0;
  for (int k0 = 0; k0 < K; k0 += 32, buf ^= 1) {
    __syncthreads();  // vmcnt drain: buf ready; prior reads of buf^1 done
    if (k0 + 32 < K) {
      const int nb = buf ^ 1, k1 = k0 + 32;
      gl_lds16(gA0 + k1, &As[nb][wb]);
      gl_lds16(gA1 + k1, &As[nb][wb + 512]);
      gl_lds16(gW0 + k1, &Bs[nb][wb]);
      gl_lds16(gW1 + k1, &Bs[nb][wb + 512]);
    }
    s16x8 af[4], bfr[4];
#pragma unroll
    for (int mt = 0; mt < 4; ++mt)
      af[mt] = *(const s16x8*)&As[buf][(wm + mt * 16 + l16) * 32 + quad * 8];
#pragma unroll
    for (int nt = 0; nt < 4; ++nt)
      bfr[nt] = *(const s16x8*)&Bs[buf][(wn + nt * 16 + l16) * 32 + quad * 8];
#pragma unroll
    for (int mt = 0; mt < 4; ++mt)
#pragma unroll
      for (int nt = 0; nt < 4; ++nt)
        acc[mt][nt] = mfma16(af[mt], bfr[nt], acc[mt][nt]);
  }

#pragma unroll
  for (int nt = 0; nt < 4; ++nt) {
    const int n = n0 + wn + nt * 16 + l16;
    const float bia = (EPI == 3) ? (n < BD ? bias[n] : bias2[n - BD]) : bias[n];
#pragma unroll
    for (int mt = 0; mt < 4; ++mt) {
      const int mb = m0 + wm + mt * 16 + quad * 4;
      if (EPI == 3 && n >= BD) {
        u16x4 pk;  // V out transposed: VT[b][n-512][k], b=m>>8, k=m&255
#pragma unroll
        for (int r = 0; r < 4; ++r) pk[r] = f2bf(acc[mt][nt][r] + bia);
        const int b = mb >> 8, k0i = mb & 255;
        *(u16x4*)&C2[((size_t)b * BD + (n - BD)) * LYK + k0i] = pk;
      } else {
#pragma unroll
        for (int r = 0; r < 4; ++r) {
          float v = acc[mt][nt][r] + bia;
          size_t idx = (size_t)(mb + r) * BD + n;
          if (EPI == 2) v += bf2f(resid[idx]);
          C[idx] = f2bf(v);
        }
      }
    }
  }
}

// ---------------- attention: persistent 8-wave blocks ---------------------
// One block per (b, h, q-chunk-phase). K [256][64] and V^T [64][256] staged
// ONCE via global_load_lds (linear LDS dest, XOR-swizzled GLOBAL source:
// K 16B-chunk ^= row&7, V chunk ^= row&31 -> fragment ds_read_b128 at the
// balanced bank minimum). P region is per-wave private (16 rows each), so
// the tile loop has ZERO barriers. Softmax: S^T=K*Q^T keeps each query's
// row in-lane; vectorized max/sum accumulators, fused exp2, cvt_pk bf16
// packing, normalization deferred to the O epilogue.
__global__ __launch_bounds__(512, 1) void attn_k(const u16* __restrict__ Q,
                                                 const u16* __restrict__ Kg,
                                                 const u16* __restrict__ VT,
                                                 const int* __restrict__ off,
                                                 u16* __restrict__ O) {
  // XCD-aware decode: each XCD sees only 16 consecutive (b,h) pairs (1 MB K+V)
  const int bid = blockIdx.x;
  const int lin = (bid & 7) * 64 + (bid >> 3);
  const int t = lin & 3;         // q-chunk phase (stride-4 over 128-q iters)
  const int h = (lin >> 2) & 7;
  const int b = lin >> 5;

  __shared__ u16 KS[256 * 64];    // 32 KB, chunk16 ^= (row&7)
  __shared__ u16 VS[64 * 256];    // 32 KB, chunk16 ^= (row&31)
  __shared__ u16 P[128 * 264];    // 66 KB, per-wave 16 rows, stride 16B-aligned

  const int tid = threadIdx.x;
  const int wave = tid >> 6, lane = tid & 63;
  const int quad = lane >> 4, l16 = lane & 15;

  // ---- stage K + V once (global_load_lds, pre-swizzled source) ----
  {
    const int c8 = lane & 7, r8 = lane >> 3;
    const u16* kbase = Kg + (size_t)(b * LYK) * BD + h * 64 + ((c8 ^ r8) << 3);
#pragma unroll
    for (int j = 0; j < 4; ++j) {
      const int blk = wave * 4 + j;
      gl_lds16(kbase + (size_t)(blk * 8 + r8) * BD, KS + blk * 512);
    }
    const int c32 = lane & 31, r2 = lane >> 5;
#pragma unroll
    for (int j = 0; j < 4; ++j) {
      const int blk = wave * 4 + j;
      const int r = blk * 2 + r2;
      gl_lds16(VT + (size_t)(b * BD + h * 64 + r) * LYK + ((c32 ^ (r & 31)) << 3),
               VS + blk * 512);
    }
  }
  __syncthreads();

  const int qbase = off[b], qend = off[b + 1];
  // per-lane swizzled K fragment column offsets (row&7 == l16&7)
  const int kc0 = ((quad ^ (l16 & 7)) << 3);
  const int kc1 = (((quad + 4) ^ (l16 & 7)) << 3);
  const int prow = (wave * 16 + l16) * 264;
  // V fragment addressing: off = vbase[n2] + ((kc*32 + quad*8) ^ vm[n2])
  int vbase[4], vm[4];
#pragma unroll
  for (int n2 = 0; n2 < 4; ++n2) {
    const int rv = n2 * 16 + l16;
    vbase[n2] = rv * 256;
    vm[n2] = (rv & 31) << 3;
  }

  for (int it = t;; it += 4) {
    const int q0 = qbase + it * 128;
    if (q0 >= qend) break;
    const int qw = q0 + wave * 16;
    if (qw >= qend) continue;  // empty wave slice; no barriers -> safe
    int qrow = qw + l16;
    if (qrow > qend - 1) qrow = qend - 1;
    const u16* qp = Q + (size_t)qrow * BD + h * 64 + quad * 8;
    const s16x8 aq0 = *(const s16x8*)qp;
    const s16x8 aq1 = *(const s16x8*)(qp + 32);

    // S^T = K Q^T : lane holds keys nt*16+quad*4+r for query l16
    f32x4 sacc[16];
#pragma unroll
    for (int nt = 0; nt < 16; ++nt) sacc[nt] = f32x4{0.f, 0.f, 0.f, 0.f};
#pragma unroll
    for (int nt = 0; nt < 16; ++nt) {
      const u16* kp = &KS[(nt * 16 + l16) * 64];
      const s16x8 k0 = *(const s16x8*)(kp + kc0);
      const s16x8 k1 = *(const s16x8*)(kp + kc1);
      sacc[nt] = mfma16(k0, aq0, sacc[nt]);
      sacc[nt] = mfma16(k1, aq1, sacc[nt]);
    }

    // softmax for query l16: vector accumulators (ILP), fused exp2
    f32x4 m4 = sacc[0];
#pragma unroll
    for (int nt = 1; nt < 16; ++nt)
#pragma unroll
      for (int r = 0; r < 4; ++r) m4[r] = fmaxf(m4[r], sacc[nt][r]);
    float mx = fmaxf(fmaxf(m4[0], m4[1]), fmaxf(m4[2], m4[3]));
    mx = fmaxf(mx, __shfl_xor(mx, 16));
    mx = fmaxf(mx, __shfl_xor(mx, 32));
    const float c1 = 0.18033688011112042f;  // 0.125 * log2(e)
    const float mc = -mx * c1;
    f32x4 s4 = f32x4{0.f, 0.f, 0.f, 0.f};
#pragma unroll
    for (int nt = 0; nt < 16; ++nt)
#pragma unroll
      for (int r = 0; r < 4; ++r) {
        const float p = __builtin_exp2f(fmaf(sacc[nt][r], c1, mc));
        sacc[nt][r] = p;
        s4[r] += p;
      }
    float sum = (s4[0] + s4[1]) + (s4[2] + s4[3]);
    sum += __shfl_xor(sum, 16);
    sum += __shfl_xor(sum, 32);
    const float inv = 1.f / sum;

    // P[query][key] bf16, UNNORMALIZED (scale folded into epilogue)
#pragma unroll
    for (int nt = 0; nt < 16; ++nt) {
      uint2 pk;
      pk.x = cvtpk(sacc[nt][0], sacc[nt][1]);
      pk.y = cvtpk(sacc[nt][2], sacc[nt][3]);
      *(uint2*)&P[prow + nt * 16 + quad * 4] = pk;
    }

    // O = P V : A-frags from own wave's P rows, B from swizzled VS
    f32x4 oacc[4];
#pragma unroll
    for (int n2 = 0; n2 < 4; ++n2) oacc[n2] = f32x4{0.f, 0.f, 0.f, 0.f};
#pragma unroll
    for (int kc = 0; kc < 8; ++kc) {
      const s16x8 ap = *(const s16x8*)&P[prow + kc * 32 + quad * 8];
#pragma unroll
      for (int n2 = 0; n2 < 4; ++n2) {
        const s16x8 bv = *(const s16x8*)&VS[vbase[n2] + ((kc * 32 + quad * 8) ^ vm[n2])];
        oacc[n2] = mfma16(ap, bv, oacc[n2]);
      }
    }

    float invr[4];
#pragma unroll
    for (int r = 0; r < 4; ++r) invr[r] = __shfl(inv, quad * 4 + r);
#pragma unroll
    for (int n2 = 0; n2 < 4; ++n2)
#pragma unroll
      for (int r = 0; r < 4; ++r) {
        const int q = qw + quad * 4 + r;
        if (q < qend)
          O[(size_t)q * BD + h * 64 + n2 * 16 + l16] = f2bf(oacc[n2][r] * invr[r]);
      }
  }
}

extern "C" void kernel_launch(void* const* d_in, const int* in_sizes, int n_in,
                              void* d_out, int out_size, void* d_ws, size_t ws_size,
                              hipStream_t stream) {
  const float* F    = (const float*)d_in[0];
  const float* yIn  = (const float*)d_in[1];
  const float* ln_g = (const float*)d_in[2];
  const float* ln_b = (const float*)d_in[3];
  const float* Wq   = (const float*)d_in[4];
  const float* Wk   = (const float*)d_in[5];
  const float* Wv   = (const float*)d_in[6];
  const float* bq   = (const float*)d_in[7];
  const float* bk   = (const float*)d_in[8];
  const float* bv   = (const float*)d_in[9];
  const float* Wo   = (const float*)d_in[10];
  const float* bo   = (const float*)d_in[11];
  const float* W1   = (const float*)d_in[12];
  const float* b1   = (const float*)d_in[13];
  const float* W2   = (const float*)d_in[14];
  const float* b2   = (const float*)d_in[15];
  const int* bids   = (const int*)d_in[16];

  char* ws = (char*)d_ws;
  size_t cur = 0;
  auto alloc = [&](size_t bytes) {
    void* p = ws + cur;
    cur += (bytes + 255) & ~(size_t)255;
    return p;
  };

  int* off   = (int*)alloc(68);
  u16* wq_b  = (u16*)alloc((size_t)262144 * 2);
  u16* wkv_b = (u16*)alloc((size_t)524288 * 2);   // [Wk; Wv] stacked, 1024x512
  u16* wo_b  = (u16*)alloc((size_t)262144 * 2);
  u16* w2_b  = (u16*)alloc((size_t)262144 * 2);
  u16* w1_b  = (u16*)alloc((size_t)393216 * 2);
  u16* y_b   = (u16*)alloc((size_t)3145728 * 2);
  u16* U     = (u16*)alloc((size_t)4096 * BD * 2);
  u16* ym    = (u16*)alloc((size_t)4096 * BD * 2);
  u16* Kb    = (u16*)alloc((size_t)4096 * BD * 2);
  u16* VT    = (u16*)alloc((size_t)NB * BD * LYK * 2);  // [b][dh_full][key]
  u16* xn    = (u16*)alloc((size_t)NTOK * BD * 2);
  u16* Qb    = (u16*)alloc((size_t)NTOK * BD * 2);
  u16* Ob    = (u16*)alloc((size_t)NTOK * BD * 2);
  u16* Zb    = (u16*)alloc((size_t)NTOK * BD * 2);

  prep<<<10561, 256, 0, stream>>>(Wq, Wk, Wv, Wo, W2, W1, yIn, F, ln_g, ln_b, bids,
                                  wq_b, wkv_b, wo_b, w2_b, w1_b, y_b, xn, off);

  // image-feature MLP (M = 4096)
  gemm64<1><<<dim3(64, 4), 256, 0, stream>>>(y_b, w1_b, b1, U, IMGD);
  gemm64<0><<<dim3(64, 4), 256, 0, stream>>>(U, w2_b, b2, ym, BD);
  // fused K/V projection, N=1024; V written transposed into VT
  gemm128<3, 0><<<dim3(32, 8), 256, 0, stream>>>(ym, wkv_b, bk, Kb, nullptr, VT, bv, BD);
  // Q projection (M = 32768), XCD-swizzled 1-D grid
  gemm128<0, 1><<<1024, 256, 0, stream>>>(xn, wq_b, bq, Qb, nullptr, nullptr, nullptr, BD);
  // cross-attention: persistent 8-wave blocks, XCD-grouped (b,h)
  attn_k<<<512, 512, 0, stream>>>(Qb, Kb, VT, off, Ob);
  // output projection + residual, XCD-swizzled
  gemm128<2, 1><<<1024, 256, 0, stream>>>(Ob, wo_b, bo, Zb, xn, nullptr, nullptr, BD);
  ln_bf16_f32<<<NTOK / 4, 256, 0, stream>>>(Zb, ln_g, ln_b, (float*)d_out);
}

// Round 2
// 338.366 us; speedup vs baseline: 1.0044x; 1.0044x over previous
//
#include <hip/hip_runtime.h>
#include <stdint.h>

#define NTOK 32768
#define BD   512
#define NB   16
#define LYK  256
#define IMGD 768

typedef __attribute__((ext_vector_type(4))) float f32x4;
typedef __attribute__((ext_vector_type(8))) short s16x8;
typedef __attribute__((ext_vector_type(4))) unsigned short u16x4;
typedef __attribute__((ext_vector_type(4))) int i32x4;
typedef unsigned short u16;

__device__ __forceinline__ float bf2f(u16 u) {
  union { uint32_t i; float f; } v; v.i = ((uint32_t)u) << 16; return v.f;
}
__device__ __forceinline__ u16 f2bf(float f) {
  union { float f; uint32_t i; } v; v.f = f;
  uint32_t r = v.i + 0x7fffu + ((v.i >> 16) & 1u);
  return (u16)(r >> 16);
}
__device__ __forceinline__ void gl_lds16(const u16* g, u16* l) {
  __builtin_amdgcn_global_load_lds(
      (const __attribute__((address_space(1))) uint32_t*)g,
      (__attribute__((address_space(3))) uint32_t*)l, 16, 0, 0);
}
__device__ __forceinline__ f32x4 mfma16(s16x8 a, s16x8 b, f32x4 c) {
  return __builtin_amdgcn_mfma_f32_16x16x32_bf16(a, b, c, 0, 0, 0);
}
__device__ __forceinline__ uint32_t cvtpk(float a, float b) {
  uint32_t r;
  asm("v_cvt_pk_bf16_f32 %0, %1, %2" : "=v"(r) : "v"(a), "v"(b));
  return r;
}

// ---- prep: fused fp32->bf16 converts + LayerNorm(F) + batch offsets ------
__global__ __launch_bounds__(256) void prep(
    const float* __restrict__ wq, const float* __restrict__ wk,
    const float* __restrict__ wv, const float* __restrict__ wo,
    const float* __restrict__ w2, const float* __restrict__ w1,
    const float* __restrict__ y,  const float* __restrict__ F,
    const float* __restrict__ g,  const float* __restrict__ be,
    const int* __restrict__ bids,
    u16* __restrict__ dq, u16* __restrict__ dkv, u16* __restrict__ dwo,
    u16* __restrict__ dw2, u16* __restrict__ dw1, u16* __restrict__ dy,
    u16* __restrict__ xn, int* __restrict__ off) {
  const int bid = blockIdx.x;
  if (bid < 2368) {
    const float* s; u16* d; int base;
    if      (bid < 128)  { s = wq; d = dq;            base = 0;   }
    else if (bid < 256)  { s = wk; d = dkv;           base = 128; }
    else if (bid < 384)  { s = wv; d = dkv + 262144;  base = 256; }
    else if (bid < 512)  { s = wo; d = dwo;           base = 384; }
    else if (bid < 640)  { s = w2; d = dw2;           base = 512; }
    else if (bid < 832)  { s = w1; d = dw1;           base = 640; }
    else                 { s = y;  d = dy;            base = 832; }
    int i = ((bid - base) * 256 + threadIdx.x) * 8;
    f32x4 a = *(const f32x4*)(s + i);
    f32x4 b = *(const f32x4*)(s + i + 4);
    s16x8 o;
#pragma unroll
    for (int j = 0; j < 4; ++j) { o[j] = (short)f2bf(a[j]); o[4 + j] = (short)f2bf(b[j]); }
    *(s16x8*)(d + i) = o;
  } else if (bid < 10560) {
    const int lane = threadIdx.x & 63;
    const size_t row = (size_t)(bid - 2368) * 4 + (threadIdx.x >> 6);
    const float* x = F + row * BD + lane * 8;
    f32x4 a = *(const f32x4*)x;
    f32x4 b = *(const f32x4*)(x + 4);
    float v[8] = {a[0], a[1], a[2], a[3], b[0], b[1], b[2], b[3]};
    float s = 0.f, s2 = 0.f;
#pragma unroll
    for (int j = 0; j < 8; ++j) { s += v[j]; s2 += v[j] * v[j]; }
#pragma unroll
    for (int m = 1; m < 64; m <<= 1) { s += __shfl_xor(s, m); s2 += __shfl_xor(s2, m); }
    float mean = s * (1.f / BD);
    float rstd = rsqrtf(s2 * (1.f / BD) - mean * mean + 1e-5f);
    const float* gp = g + lane * 8;
    const float* bp = be + lane * 8;
    s16x8 o;
#pragma unroll
    for (int j = 0; j < 8; ++j) o[j] = (short)f2bf((v[j] - mean) * rstd * gp[j] + bp[j]);
    *(s16x8*)(xn + row * BD + lane * 8) = o;
  } else {
    int b = threadIdx.x;
    if (b > NB) return;
    int lo = 0, hi = NTOK;
    while (lo < hi) { int mid = (lo + hi) >> 1; if (bids[mid] < b) lo = mid + 1; else hi = mid; }
    off[b] = lo;
  }
}

// ---------------- LayerNorm: bf16 in -> fp32 out ----------------
__global__ __launch_bounds__(256) void ln_bf16_f32(const u16* __restrict__ Z,
                                                   const float* __restrict__ g,
                                                   const float* __restrict__ be,
                                                   float* __restrict__ out) {
  const int lane = threadIdx.x & 63;
  const size_t row = (size_t)blockIdx.x * 4 + (threadIdx.x >> 6);
  s16x8 zv = *(const s16x8*)(Z + row * BD + lane * 8);
  float v[8];
#pragma unroll
  for (int j = 0; j < 8; ++j) v[j] = bf2f((u16)zv[j]);
  float s = 0.f, s2 = 0.f;
#pragma unroll
  for (int j = 0; j < 8; ++j) { s += v[j]; s2 += v[j] * v[j]; }
#pragma unroll
  for (int m = 1; m < 64; m <<= 1) { s += __shfl_xor(s, m); s2 += __shfl_xor(s2, m); }
  float mean = s * (1.f / BD);
  float rstd = rsqrtf(s2 * (1.f / BD) - mean * mean + 1e-5f);
  const float* gp = g + lane * 8;
  const float* bp = be + lane * 8;
  f32x4 o0, o1;
#pragma unroll
  for (int j = 0; j < 4; ++j) o0[j] = (v[j] - mean) * rstd * gp[j] + bp[j];
#pragma unroll
  for (int j = 0; j < 4; ++j) o1[j] = (v[4 + j] - mean) * rstd * gp[4 + j] + bp[4 + j];
  float* op = out + row * BD + lane * 8;
  *(f32x4*)op = o0;
  *(f32x4*)(op + 4) = o1;
}

// ---------------- TM=64 NT GEMM (small M), BK=32 --------------------------
template <int EPI>
__global__ __launch_bounds__(256, 2) void gemm64(const u16* __restrict__ A,
                                                 const u16* __restrict__ W,
                                                 const float* __restrict__ bias,
                                                 u16* __restrict__ C, int K) {
  __shared__ u16 As[64 * 32];
  __shared__ u16 Bs[128 * 32];
  const int tid = threadIdx.x;
  const int wave = tid >> 6, lane = tid & 63;
  const int wn = wave * 32;
  const int quad = lane >> 4, l16 = lane & 15;
  const int m0 = blockIdx.x * 64, n0 = blockIdx.y * 128;

  f32x4 acc[4][2];
#pragma unroll
  for (int i = 0; i < 4; ++i)
#pragma unroll
    for (int j = 0; j < 2; ++j) acc[i][j] = f32x4{0.f, 0.f, 0.f, 0.f};

  const int scol = (lane & 3) * 8;
  const u16* gA0 = A + (size_t)(m0 + wave * 16 + (lane >> 2)) * K + scol;
  const u16* gW0 = W + (size_t)(n0 + wave * 32 + (lane >> 2)) * K + scol;
  const u16* gW1 = gW0 + (size_t)16 * K;
  u16* lA = As + wave * 512;
  u16* lB = Bs + wave * 1024;

  for (int k0 = 0; k0 < K; k0 += 32) {
    __syncthreads();
    gl_lds16(gA0 + k0, lA);
    gl_lds16(gW0 + k0, lB);
    gl_lds16(gW1 + k0, lB + 512);
    __syncthreads();
    s16x8 af[4], bfr[2];
#pragma unroll
    for (int mt = 0; mt < 4; ++mt)
      af[mt] = *(const s16x8*)&As[(mt * 16 + l16) * 32 + quad * 8];
#pragma unroll
    for (int nt = 0; nt < 2; ++nt)
      bfr[nt] = *(const s16x8*)&Bs[(wn + nt * 16 + l16) * 32 + quad * 8];
#pragma unroll
    for (int mt = 0; mt < 4; ++mt)
#pragma unroll
      for (int nt = 0; nt < 2; ++nt)
        acc[mt][nt] = mfma16(af[mt], bfr[nt], acc[mt][nt]);
  }

#pragma unroll
  for (int nt = 0; nt < 2; ++nt) {
    const int n = n0 + wn + nt * 16 + l16;
    const float bia = bias[n];
#pragma unroll
    for (int mt = 0; mt < 4; ++mt) {
      const int mb = m0 + mt * 16 + quad * 4;
#pragma unroll
      for (int r = 0; r < 4; ++r) {
        float v = acc[mt][nt][r] + bia;
        if (EPI == 1) v = 0.5f * v * (1.f + erff(v * 0.70710678118654752f));
        C[(size_t)(mb + r) * BD + n] = f2bf(v);
      }
    }
  }
}

// ---------------- TM=128 NT GEMM, BK=32, double-buffered ------------------
// EPI 0: bf16 out; 2: +resid bf16; 3: dual K/V out, V transposed into C2
template <int EPI, int SWZ>
__global__ __launch_bounds__(256, 2) void gemm128(const u16* __restrict__ A,
                                                  const u16* __restrict__ W,
                                                  const float* __restrict__ bias,
                                                  u16* __restrict__ C,
                                                  const u16* __restrict__ resid,
                                                  u16* __restrict__ C2,
                                                  const float* __restrict__ bias2,
                                                  int K) {
  __shared__ u16 As[2][128 * 32];
  __shared__ u16 Bs[2][128 * 32];
  const int tid = threadIdx.x;
  const int wave = tid >> 6, lane = tid & 63;
  const int wm = (wave & 1) * 64, wn = (wave >> 1) * 64;
  const int quad = lane >> 4, l16 = lane & 15;
  int m_t, n_t;
  if (SWZ) {  // bid&7 = XCD slot; N-blocks sharing an A-tile on one XCD
    const int bid = blockIdx.x;
    const int xcd = bid & 7, j = bid >> 3;
    n_t = j & 3;
    m_t = xcd + (j >> 2) * 8;
  } else {
    m_t = blockIdx.x; n_t = blockIdx.y;
  }
  const int m0 = m_t * 128, n0 = n_t * 128;

  f32x4 acc[4][4];
#pragma unroll
  for (int i = 0; i < 4; ++i)
#pragma unroll
    for (int j = 0; j < 4; ++j) acc[i][j] = f32x4{0.f, 0.f, 0.f, 0.f};

  const int srow = wave * 32 + (lane >> 2);
  const int scol = (lane & 3) * 8;
  const u16* gA0 = A + (size_t)(m0 + srow) * K + scol;
  const u16* gA1 = gA0 + (size_t)16 * K;
  const u16* gW0 = W + (size_t)(n0 + srow) * K + scol;
  const u16* gW1 = gW0 + (size_t)16 * K;
  const int wb = wave * 1024;

  // prologue: fill buffer 0
  gl_lds16(gA0, &As[0][wb]);
  gl_lds16(gA1, &As[0][wb + 512]);
  gl_lds16(gW0, &Bs[0][wb]);
  gl_lds16(gW1, &Bs[0][wb + 512]);

  int buf = 0;
  for (int k0 = 0; k0 < K; k0 += 32, buf ^= 1) {
    __syncthreads();  // vmcnt drain: buf ready; prior reads of buf^1 done
    if (k0 + 32 < K) {
      const int nb = buf ^ 1, k1 = k0 + 32;
      gl_lds16(gA0 + k1, &As[nb][wb]);
      gl_lds16(gA1 + k1, &As[nb][wb + 512]);
      gl_lds16(gW0 + k1, &Bs[nb][wb]);
      gl_lds16(gW1 + k1, &Bs[nb][wb + 512]);
    }
    s16x8 af[4], bfr[4];
#pragma unroll
    for (int mt = 0; mt < 4; ++mt)
      af[mt] = *(const s16x8*)&As[buf][(wm + mt * 16 + l16) * 32 + quad * 8];
#pragma unroll
    for (int nt = 0; nt < 4; ++nt)
      bfr[nt] = *(const s16x8*)&Bs[buf][(wn + nt * 16 + l16) * 32 + quad * 8];
#pragma unroll
    for (int mt = 0; mt < 4; ++mt)
#pragma unroll
      for (int nt = 0; nt < 4; ++nt)
        acc[mt][nt] = mfma16(af[mt], bfr[nt], acc[mt][nt]);
  }

#pragma unroll
  for (int nt = 0; nt < 4; ++nt) {
    const int n = n0 + wn + nt * 16 + l16;
    const float bia = (EPI == 3) ? (n < BD ? bias[n] : bias2[n - BD]) : bias[n];
#pragma unroll
    for (int mt = 0; mt < 4; ++mt) {
      const int mb = m0 + wm + mt * 16 + quad * 4;
      if (EPI == 3 && n >= BD) {
        u16x4 pk;  // V out transposed: VT[b][n-512][k], b=m>>8, k=m&255
#pragma unroll
        for (int r = 0; r < 4; ++r) pk[r] = f2bf(acc[mt][nt][r] + bia);
        const int b = mb >> 8, k0i = mb & 255;
        *(u16x4*)&C2[((size_t)b * BD + (n - BD)) * LYK + k0i] = pk;
      } else {
#pragma unroll
        for (int r = 0; r < 4; ++r) {
          float v = acc[mt][nt][r] + bia;
          size_t idx = (size_t)(mb + r) * BD + n;
          if (EPI == 2) v += bf2f(resid[idx]);
          C[idx] = f2bf(v);
        }
      }
    }
  }
}

// ---------------- attention: persistent 8-wave blocks, in-register P ------
// K [256][64] and V^T [64][256] staged ONCE via global_load_lds (linear LDS
// dest, XOR-swizzled GLOBAL source). LDS = 64 KB -> 2 blocks/CU = 4
// waves/SIMD. P never touches LDS: after swapped QK^T, lane (l16,q) holds
// P[query=l16][keys 16nt+4q+r]; cvt_pk packs pairs, then per k-chunk one
// v_permlane32_swap + v_permlane16_swap per word pair redistributes across
// quads into the exact 16x16x32 A-fragment (all swap outputs used).
// Softmax normalization deferred to the O epilogue.
__global__ __launch_bounds__(512, 4) void attn_k(const u16* __restrict__ Q,
                                                 const u16* __restrict__ Kg,
                                                 const u16* __restrict__ VT,
                                                 const int* __restrict__ off,
                                                 u16* __restrict__ O) {
  // XCD-aware decode: each XCD sees only 16 consecutive (b,h) pairs (1 MB K+V)
  const int bid = blockIdx.x;
  const int lin = (bid & 7) * 64 + (bid >> 3);
  const int t = lin & 3;         // q-chunk phase (stride-4 over 128-q iters)
  const int h = (lin >> 2) & 7;
  const int b = lin >> 5;

  __shared__ u16 KS[256 * 64];    // 32 KB, chunk16 ^= (row&7)
  __shared__ u16 VS[64 * 256];    // 32 KB, chunk16 ^= (row&31)

  const int tid = threadIdx.x;
  const int wave = tid >> 6, lane = tid & 63;
  const int quad = lane >> 4, l16 = lane & 15;

  // ---- stage K + V once (global_load_lds, pre-swizzled source) ----
  {
    const int c8 = lane & 7, r8 = lane >> 3;
    const u16* kbase = Kg + (size_t)(b * LYK) * BD + h * 64 + ((c8 ^ r8) << 3);
#pragma unroll
    for (int j = 0; j < 4; ++j) {
      const int blk = wave * 4 + j;
      gl_lds16(kbase + (size_t)(blk * 8 + r8) * BD, KS + blk * 512);
    }
    const int c32 = lane & 31, r2 = lane >> 5;
#pragma unroll
    for (int j = 0; j < 4; ++j) {
      const int blk = wave * 4 + j;
      const int r = blk * 2 + r2;
      gl_lds16(VT + (size_t)(b * BD + h * 64 + r) * LYK + ((c32 ^ (r & 31)) << 3),
               VS + blk * 512);
    }
  }
  __syncthreads();

  const int qbase = off[b], qend = off[b + 1];
  // per-lane swizzled K fragment column offsets (row&7 == l16&7)
  const int kc0 = ((quad ^ (l16 & 7)) << 3);
  const int kc1 = (((quad + 4) ^ (l16 & 7)) << 3);
  // V fragment addressing: off = vbase[n2] + ((kc*32 + quad*8) ^ vm[n2])
  int vbase[4], vm[4];
#pragma unroll
  for (int n2 = 0; n2 < 4; ++n2) {
    const int rv = n2 * 16 + l16;
    vbase[n2] = rv * 256;
    vm[n2] = (rv & 31) << 3;
  }

  for (int it = t;; it += 4) {
    const int q0 = qbase + it * 128;
    if (q0 >= qend) break;
    const int qw = q0 + wave * 16;
    if (qw >= qend) continue;  // empty wave slice; no barriers in loop -> safe
    int qrow = qw + l16;
    if (qrow > qend - 1) qrow = qend - 1;
    const u16* qp = Q + (size_t)qrow * BD + h * 64 + quad * 8;
    const s16x8 aq0 = *(const s16x8*)qp;
    const s16x8 aq1 = *(const s16x8*)(qp + 32);

    // S^T = K Q^T : lane holds keys nt*16+quad*4+r for query l16
    f32x4 sacc[16];
#pragma unroll
    for (int nt = 0; nt < 16; ++nt) sacc[nt] = f32x4{0.f, 0.f, 0.f, 0.f};
#pragma unroll
    for (int nt = 0; nt < 16; ++nt) {
      const u16* kp = &KS[(nt * 16 + l16) * 64];
      const s16x8 k0 = *(const s16x8*)(kp + kc0);
      const s16x8 k1 = *(const s16x8*)(kp + kc1);
      sacc[nt] = mfma16(k0, aq0, sacc[nt]);
      sacc[nt] = mfma16(k1, aq1, sacc[nt]);
    }

    // softmax max for query l16: in-lane vector max + 2 quad shuffles
    f32x4 m4 = sacc[0];
#pragma unroll
    for (int nt = 1; nt < 16; ++nt)
#pragma unroll
      for (int r = 0; r < 4; ++r) m4[r] = fmaxf(m4[r], sacc[nt][r]);
    float mx = fmaxf(fmaxf(m4[0], m4[1]), fmaxf(m4[2], m4[3]));
    mx = fmaxf(mx, __shfl_xor(mx, 16));
    mx = fmaxf(mx, __shfl_xor(mx, 32));
    const float c1 = 0.18033688011112042f;  // 0.125 * log2(e)
    const float mc = -mx * c1;

    // fused exp2 + sum + bf16 pack (sacc dies progressively -> low VGPR peak)
    f32x4 s4 = f32x4{0.f, 0.f, 0.f, 0.f};
    uint32_t pk[32];
#pragma unroll
    for (int nt = 0; nt < 16; ++nt) {
      const float p0 = __builtin_exp2f(fmaf(sacc[nt][0], c1, mc));
      const float p1 = __builtin_exp2f(fmaf(sacc[nt][1], c1, mc));
      const float p2 = __builtin_exp2f(fmaf(sacc[nt][2], c1, mc));
      const float p3 = __builtin_exp2f(fmaf(sacc[nt][3], c1, mc));
      s4[0] += p0; s4[1] += p1; s4[2] += p2; s4[3] += p3;
      pk[2 * nt]     = cvtpk(p0, p1);
      pk[2 * nt + 1] = cvtpk(p2, p3);
    }
    float sum = (s4[0] + s4[1]) + (s4[2] + s4[3]);
    sum += __shfl_xor(sum, 16);
    sum += __shfl_xor(sum, 32);
    const float inv = 1.f / sum;

    // O = P V : A-frags built in-register via quad permlane swaps
    f32x4 oacc[4];
#pragma unroll
    for (int n2 = 0; n2 < 4; ++n2) oacc[n2] = f32x4{0.f, 0.f, 0.f, 0.f};
#pragma unroll
    for (int kc = 0; kc < 8; ++kc) {
      uint32_t x0 = pk[4 * kc],     y0 = pk[4 * kc + 2];
      uint32_t x1 = pk[4 * kc + 1], y1 = pk[4 * kc + 3];
      asm("v_permlane32_swap_b32 %0, %1" : "+v"(x0), "+v"(y0));
      asm("v_permlane16_swap_b32 %0, %1" : "+v"(x0), "+v"(y0));
      asm("v_permlane32_swap_b32 %0, %1" : "+v"(x1), "+v"(y1));
      asm("v_permlane16_swap_b32 %0, %1" : "+v"(x1), "+v"(y1));
      i32x4 aw;
      aw[0] = (int)x0; aw[1] = (int)x1; aw[2] = (int)y0; aw[3] = (int)y1;
      const s16x8 ap = __builtin_bit_cast(s16x8, aw);
#pragma unroll
      for (int n2 = 0; n2 < 4; ++n2) {
        const s16x8 bv = *(const s16x8*)&VS[vbase[n2] + ((kc * 32 + quad * 8) ^ vm[n2])];
        oacc[n2] = mfma16(ap, bv, oacc[n2]);
      }
    }

    float invr[4];
#pragma unroll
    for (int r = 0; r < 4; ++r) invr[r] = __shfl(inv, quad * 4 + r);
#pragma unroll
    for (int n2 = 0; n2 < 4; ++n2)
#pragma unroll
      for (int r = 0; r < 4; ++r) {
        const int q = qw + quad * 4 + r;
        if (q < qend)
          O[(size_t)q * BD + h * 64 + n2 * 16 + l16] = f2bf(oacc[n2][r] * invr[r]);
      }
  }
}

extern "C" void kernel_launch(void* const* d_in, const int* in_sizes, int n_in,
                              void* d_out, int out_size, void* d_ws, size_t ws_size,
                              hipStream_t stream) {
  const float* F    = (const float*)d_in[0];
  const float* yIn  = (const float*)d_in[1];
  const float* ln_g = (const float*)d_in[2];
  const float* ln_b = (const float*)d_in[3];
  const float* Wq   = (const float*)d_in[4];
  const float* Wk   = (const float*)d_in[5];
  const float* Wv   = (const float*)d_in[6];
  const float* bq   = (const float*)d_in[7];
  const float* bk   = (const float*)d_in[8];
  const float* bv   = (const float*)d_in[9];
  const float* Wo   = (const float*)d_in[10];
  const float* bo   = (const float*)d_in[11];
  const float* W1   = (const float*)d_in[12];
  const float* b1   = (const float*)d_in[13];
  const float* W2   = (const float*)d_in[14];
  const float* b2   = (const float*)d_in[15];
  const int* bids   = (const int*)d_in[16];

  char* ws = (char*)d_ws;
  size_t cur = 0;
  auto alloc = [&](size_t bytes) {
    void* p = ws + cur;
    cur += (bytes + 255) & ~(size_t)255;
    return p;
  };

  int* off   = (int*)alloc(68);
  u16* wq_b  = (u16*)alloc((size_t)262144 * 2);
  u16* wkv_b = (u16*)alloc((size_t)524288 * 2);   // [Wk; Wv] stacked, 1024x512
  u16* wo_b  = (u16*)alloc((size_t)262144 * 2);
  u16* w2_b  = (u16*)alloc((size_t)262144 * 2);
  u16* w1_b  = (u16*)alloc((size_t)393216 * 2);
  u16* y_b   = (u16*)alloc((size_t)3145728 * 2);
  u16* U     = (u16*)alloc((size_t)4096 * BD * 2);
  u16* ym    = (u16*)alloc((size_t)4096 * BD * 2);
  u16* Kb    = (u16*)alloc((size_t)4096 * BD * 2);
  u16* VT    = (u16*)alloc((size_t)NB * BD * LYK * 2);  // [b][dh_full][key]
  u16* xn    = (u16*)alloc((size_t)NTOK * BD * 2);
  u16* Qb    = (u16*)alloc((size_t)NTOK * BD * 2);
  u16* Ob    = (u16*)alloc((size_t)NTOK * BD * 2);
  u16* Zb    = (u16*)alloc((size_t)NTOK * BD * 2);

  prep<<<10561, 256, 0, stream>>>(Wq, Wk, Wv, Wo, W2, W1, yIn, F, ln_g, ln_b, bids,
                                  wq_b, wkv_b, wo_b, w2_b, w1_b, y_b, xn, off);

  // image-feature MLP (M = 4096)
  gemm64<1><<<dim3(64, 4), 256, 0, stream>>>(y_b, w1_b, b1, U, IMGD);
  gemm64<0><<<dim3(64, 4), 256, 0, stream>>>(U, w2_b, b2, ym, BD);
  // fused K/V projection, N=1024; V written transposed into VT
  gemm128<3, 0><<<dim3(32, 8), 256, 0, stream>>>(ym, wkv_b, bk, Kb, nullptr, VT, bv, BD);
  // Q projection (M = 32768), XCD-swizzled 1-D grid
  gemm128<0, 1><<<1024, 256, 0, stream>>>(xn, wq_b, bq, Qb, nullptr, nullptr, nullptr, BD);
  // cross-attention: persistent 8-wave blocks, in-register P, 2 blocks/CU
  attn_k<<<512, 512, 0, stream>>>(Qb, Kb, VT, off, Ob);
  // output projection + residual, XCD-swizzled
  gemm128<2, 1><<<1024, 256, 0, stream>>>(Ob, wo_b, bo, Zb, xn, nullptr, nullptr, BD);
  ln_bf16_f32<<<NTOK / 4, 256, 0, stream>>>(Zb, ln_g, ln_b, (float*)d_out);
}

// Round 5
// 328.865 us; speedup vs baseline: 1.0334x; 1.0289x over previous
//
#include <hip/hip_runtime.h>
#include <stdint.h>

#define NTOK 32768
#define BD   512
#define NB   16
#define LYK  256
#define IMGD 768

typedef __attribute__((ext_vector_type(4))) float f32x4;
typedef __attribute__((ext_vector_type(16))) float f32x16;
typedef __attribute__((ext_vector_type(8))) short s16x8;
typedef __attribute__((ext_vector_type(4))) unsigned short u16x4;
typedef __attribute__((ext_vector_type(4))) int i32x4;
typedef unsigned short u16;

__device__ __forceinline__ float bf2f(u16 u) {
  union { uint32_t i; float f; } v; v.i = ((uint32_t)u) << 16; return v.f;
}
__device__ __forceinline__ u16 f2bf(float f) {
  union { float f; uint32_t i; } v; v.f = f;
  uint32_t r = v.i + 0x7fffu + ((v.i >> 16) & 1u);
  return (u16)(r >> 16);
}
__device__ __forceinline__ void gl_lds16(const u16* g, u16* l) {
  __builtin_amdgcn_global_load_lds(
      (const __attribute__((address_space(1))) uint32_t*)g,
      (__attribute__((address_space(3))) uint32_t*)l, 16, 0, 0);
}
__device__ __forceinline__ f32x4 mfma16(s16x8 a, s16x8 b, f32x4 c) {
  return __builtin_amdgcn_mfma_f32_16x16x32_bf16(a, b, c, 0, 0, 0);
}
__device__ __forceinline__ f32x16 mfma32(s16x8 a, s16x8 b, f32x16 c) {
  return __builtin_amdgcn_mfma_f32_32x32x16_bf16(a, b, c, 0, 0, 0);
}
__device__ __forceinline__ uint32_t cvtpk(float a, float b) {
  uint32_t r;
  asm("v_cvt_pk_bf16_f32 %0, %1, %2" : "=v"(r) : "v"(a), "v"(b));
  return r;
}

// ---- prep: fused fp32->bf16 converts + LayerNorm(F) + batch offsets ------
__global__ __launch_bounds__(256) void prep(
    const float* __restrict__ wq, const float* __restrict__ wk,
    const float* __restrict__ wv, const float* __restrict__ wo,
    const float* __restrict__ w2, const float* __restrict__ w1,
    const float* __restrict__ y,  const float* __restrict__ F,
    const float* __restrict__ g,  const float* __restrict__ be,
    const int* __restrict__ bids,
    u16* __restrict__ dq, u16* __restrict__ dkv, u16* __restrict__ dwo,
    u16* __restrict__ dw2, u16* __restrict__ dw1, u16* __restrict__ dy,
    u16* __restrict__ xn, int* __restrict__ off) {
  const int bid = blockIdx.x;
  if (bid < 2368) {
    const float* s; u16* d; int base;
    if      (bid < 128)  { s = wq; d = dq;            base = 0;   }
    else if (bid < 256)  { s = wk; d = dkv;           base = 128; }
    else if (bid < 384)  { s = wv; d = dkv + 262144;  base = 256; }
    else if (bid < 512)  { s = wo; d = dwo;           base = 384; }
    else if (bid < 640)  { s = w2; d = dw2;           base = 512; }
    else if (bid < 832)  { s = w1; d = dw1;           base = 640; }
    else                 { s = y;  d = dy;            base = 832; }
    int i = ((bid - base) * 256 + threadIdx.x) * 8;
    f32x4 a = *(const f32x4*)(s + i);
    f32x4 b = *(const f32x4*)(s + i + 4);
    s16x8 o;
#pragma unroll
    for (int j = 0; j < 4; ++j) { o[j] = (short)f2bf(a[j]); o[4 + j] = (short)f2bf(b[j]); }
    *(s16x8*)(d + i) = o;
  } else if (bid < 10560) {
    const int lane = threadIdx.x & 63;
    const size_t row = (size_t)(bid - 2368) * 4 + (threadIdx.x >> 6);
    const float* x = F + row * BD + lane * 8;
    f32x4 a = *(const f32x4*)x;
    f32x4 b = *(const f32x4*)(x + 4);
    float v[8] = {a[0], a[1], a[2], a[3], b[0], b[1], b[2], b[3]};
    float s = 0.f, s2 = 0.f;
#pragma unroll
    for (int j = 0; j < 8; ++j) { s += v[j]; s2 += v[j] * v[j]; }
#pragma unroll
    for (int m = 1; m < 64; m <<= 1) { s += __shfl_xor(s, m); s2 += __shfl_xor(s2, m); }
    float mean = s * (1.f / BD);
    float rstd = rsqrtf(s2 * (1.f / BD) - mean * mean + 1e-5f);
    const float* gp = g + lane * 8;
    const float* bp = be + lane * 8;
    s16x8 o;
#pragma unroll
    for (int j = 0; j < 8; ++j) o[j] = (short)f2bf((v[j] - mean) * rstd * gp[j] + bp[j]);
    *(s16x8*)(xn + row * BD + lane * 8) = o;
  } else {
    int b = threadIdx.x;
    if (b > NB) return;
    int lo = 0, hi = NTOK;
    while (lo < hi) { int mid = (lo + hi) >> 1; if (bids[mid] < b) lo = mid + 1; else hi = mid; }
    off[b] = lo;
  }
}

// ---------------- LayerNorm: bf16 in -> fp32 out ----------------
__global__ __launch_bounds__(256) void ln_bf16_f32(const u16* __restrict__ Z,
                                                   const float* __restrict__ g,
                                                   const float* __restrict__ be,
                                                   float* __restrict__ out) {
  const int lane = threadIdx.x & 63;
  const size_t row = (size_t)blockIdx.x * 4 + (threadIdx.x >> 6);
  s16x8 zv = *(const s16x8*)(Z + row * BD + lane * 8);
  float v[8];
#pragma unroll
  for (int j = 0; j < 8; ++j) v[j] = bf2f((u16)zv[j]);
  float s = 0.f, s2 = 0.f;
#pragma unroll
  for (int j = 0; j < 8; ++j) { s += v[j]; s2 += v[j] * v[j]; }
#pragma unroll
  for (int m = 1; m < 64; m <<= 1) { s += __shfl_xor(s, m); s2 += __shfl_xor(s2, m); }
  float mean = s * (1.f / BD);
  float rstd = rsqrtf(s2 * (1.f / BD) - mean * mean + 1e-5f);
  const float* gp = g + lane * 8;
  const float* bp = be + lane * 8;
  f32x4 o0, o1;
#pragma unroll
  for (int j = 0; j < 4; ++j) o0[j] = (v[j] - mean) * rstd * gp[j] + bp[j];
#pragma unroll
  for (int j = 0; j < 4; ++j) o1[j] = (v[4 + j] - mean) * rstd * gp[4 + j] + bp[4 + j];
  float* op = out + row * BD + lane * 8;
  *(f32x4*)op = o0;
  *(f32x4*)(op + 4) = o1;
}

// ---------------- TM=64 NT GEMM (small M), BK=32 --------------------------
template <int EPI>
__global__ __launch_bounds__(256, 2) void gemm64(const u16* __restrict__ A,
                                                 const u16* __restrict__ W,
                                                 const float* __restrict__ bias,
                                                 u16* __restrict__ C, int K) {
  __shared__ u16 As[64 * 32];
  __shared__ u16 Bs[128 * 32];
  const int tid = threadIdx.x;
  const int wave = tid >> 6, lane = tid & 63;
  const int wn = wave * 32;
  const int quad = lane >> 4, l16 = lane & 15;
  const int m0 = blockIdx.x * 64, n0 = blockIdx.y * 128;

  f32x4 acc[4][2];
#pragma unroll
  for (int i = 0; i < 4; ++i)
#pragma unroll
    for (int j = 0; j < 2; ++j) acc[i][j] = f32x4{0.f, 0.f, 0.f, 0.f};

  const int scol = (lane & 3) * 8;
  const u16* gA0 = A + (size_t)(m0 + wave * 16 + (lane >> 2)) * K + scol;
  const u16* gW0 = W + (size_t)(n0 + wave * 32 + (lane >> 2)) * K + scol;
  const u16* gW1 = gW0 + (size_t)16 * K;
  u16* lA = As + wave * 512;
  u16* lB = Bs + wave * 1024;

  for (int k0 = 0; k0 < K; k0 += 32) {
    __syncthreads();
    gl_lds16(gA0 + k0, lA);
    gl_lds16(gW0 + k0, lB);
    gl_lds16(gW1 + k0, lB + 512);
    __syncthreads();
    s16x8 af[4], bfr[2];
#pragma unroll
    for (int mt = 0; mt < 4; ++mt)
      af[mt] = *(const s16x8*)&As[(mt * 16 + l16) * 32 + quad * 8];
#pragma unroll
    for (int nt = 0; nt < 2; ++nt)
      bfr[nt] = *(const s16x8*)&Bs[(wn + nt * 16 + l16) * 32 + quad * 8];
#pragma unroll
    for (int mt = 0; mt < 4; ++mt)
#pragma unroll
      for (int nt = 0; nt < 2; ++nt)
        acc[mt][nt] = mfma16(af[mt], bfr[nt], acc[mt][nt]);
  }

#pragma unroll
  for (int nt = 0; nt < 2; ++nt) {
    const int n = n0 + wn + nt * 16 + l16;
    const float bia = bias[n];
#pragma unroll
    for (int mt = 0; mt < 4; ++mt) {
      const int mb = m0 + mt * 16 + quad * 4;
#pragma unroll
      for (int r = 0; r < 4; ++r) {
        float v = acc[mt][nt][r] + bia;
        if (EPI == 1) v = 0.5f * v * (1.f + erff(v * 0.70710678118654752f));
        C[(size_t)(mb + r) * BD + n] = f2bf(v);
      }
    }
  }
}

// ---------------- TM=128 NT GEMM, BK=32, double-buffered ------------------
// EPI 0: bf16 out; 2: +resid bf16; 3: dual K/V out, V transposed into C2
template <int EPI, int SWZ>
__global__ __launch_bounds__(256, 2) void gemm128(const u16* __restrict__ A,
                                                  const u16* __restrict__ W,
                                                  const float* __restrict__ bias,
                                                  u16* __restrict__ C,
                                                  const u16* __restrict__ resid,
                                                  u16* __restrict__ C2,
                                                  const float* __restrict__ bias2,
                                                  int K) {
  __shared__ u16 As[2][128 * 32];
  __shared__ u16 Bs[2][128 * 32];
  const int tid = threadIdx.x;
  const int wave = tid >> 6, lane = tid & 63;
  const int wm = (wave & 1) * 64, wn = (wave >> 1) * 64;
  const int quad = lane >> 4, l16 = lane & 15;
  int m_t, n_t;
  if (SWZ) {  // bid&7 = XCD slot; N-blocks sharing an A-tile on one XCD
    const int bid = blockIdx.x;
    const int xcd = bid & 7, j = bid >> 3;
    n_t = j & 3;
    m_t = xcd + (j >> 2) * 8;
  } else {
    m_t = blockIdx.x; n_t = blockIdx.y;
  }
  const int m0 = m_t * 128, n0 = n_t * 128;

  f32x4 acc[4][4];
#pragma unroll
  for (int i = 0; i < 4; ++i)
#pragma unroll
    for (int j = 0; j < 4; ++j) acc[i][j] = f32x4{0.f, 0.f, 0.f, 0.f};

  const int srow = wave * 32 + (lane >> 2);
  const int scol = (lane & 3) * 8;
  const u16* gA0 = A + (size_t)(m0 + srow) * K + scol;
  const u16* gA1 = gA0 + (size_t)16 * K;
  const u16* gW0 = W + (size_t)(n0 + srow) * K + scol;
  const u16* gW1 = gW0 + (size_t)16 * K;
  const int wb = wave * 1024;

  // prologue: fill buffer 0
  gl_lds16(gA0, &As[0][wb]);
  gl_lds16(gA1, &As[0][wb + 512]);
  gl_lds16(gW0, &Bs[0][wb]);
  gl_lds16(gW1, &Bs[0][wb + 512]);

  int buf = 0;
  for (int k0 = 0; k0 < K; k0 += 32, buf ^= 1) {
    __syncthreads();  // vmcnt drain: buf ready; prior reads of buf^1 done
    if (k0 + 32 < K) {
      const int nb = buf ^ 1, k1 = k0 + 32;
      gl_lds16(gA0 + k1, &As[nb][wb]);
      gl_lds16(gA1 + k1, &As[nb][wb + 512]);
      gl_lds16(gW0 + k1, &Bs[nb][wb]);
      gl_lds16(gW1 + k1, &Bs[nb][wb + 512]);
    }
    s16x8 af[4], bfr[4];
#pragma unroll
    for (int mt = 0; mt < 4; ++mt)
      af[mt] = *(const s16x8*)&As[buf][(wm + mt * 16 + l16) * 32 + quad * 8];
#pragma unroll
    for (int nt = 0; nt < 4; ++nt)
      bfr[nt] = *(const s16x8*)&Bs[buf][(wn + nt * 16 + l16) * 32 + quad * 8];
#pragma unroll
    for (int mt = 0; mt < 4; ++mt)
#pragma unroll
      for (int nt = 0; nt < 4; ++nt)
        acc[mt][nt] = mfma16(af[mt], bfr[nt], acc[mt][nt]);
  }

#pragma unroll
  for (int nt = 0; nt < 4; ++nt) {
    const int n = n0 + wn + nt * 16 + l16;
    const float bia = (EPI == 3) ? (n < BD ? bias[n] : bias2[n - BD]) : bias[n];
#pragma unroll
    for (int mt = 0; mt < 4; ++mt) {
      const int mb = m0 + wm + mt * 16 + quad * 4;
      if (EPI == 3 && n >= BD) {
        u16x4 pk;  // V out transposed: VT[b][n-512][k], b=m>>8, k=m&255
#pragma unroll
        for (int r = 0; r < 4; ++r) pk[r] = f2bf(acc[mt][nt][r] + bia);
        const int b = mb >> 8, k0i = mb & 255;
        *(u16x4*)&C2[((size_t)b * BD + (n - BD)) * LYK + k0i] = pk;
      } else {
#pragma unroll
        for (int r = 0; r < 4; ++r) {
          float v = acc[mt][nt][r] + bia;
          size_t idx = (size_t)(mb + r) * BD + n;
          if (EPI == 2) v += bf2f(resid[idx]);
          C[idx] = f2bf(v);
        }
      }
    }
  }
}

// ---------------- attention: 32x32 MFMA, 32 queries/wave ------------------
// One block per (128-query chunk, head, batch); 4 waves x 32 queries.
// K [256][64] and V^T [64][256] staged via global_load_lds (linear LDS dest,
// XOR-swizzled GLOBAL source). S^T = K Q^T with mfma_32x32x16: D col = query
// = lane&31 -> softmax is in-lane + ONE shfl_xor(32). P stays in registers:
// cvt_pk packs normalized pairs; 2 permlane32_swap per 16-key chunk build the
// exact 32x32x16 A-fragment ([D_lo|S_lo],[D_hi|S_hi] recombination). A-frag
// LDS traffic per MAC is half the 16x16 variant's.
__global__ __launch_bounds__(256, 2) void attn_k(const u16* __restrict__ Q,
                                                 const u16* __restrict__ Kg,
                                                 const u16* __restrict__ VT,
                                                 const int* __restrict__ off,
                                                 u16* __restrict__ O) {
  const int chunk = blockIdx.x, h = blockIdx.y, b = blockIdx.z;
  const int qbase = off[b], qend = off[b + 1];
  const int q0 = qbase + chunk * 128;
  if (q0 >= qend) return;

  __shared__ u16 KS[256 * 64];    // 32 KB, 16B-chunk c stored at c^(row&7)
  __shared__ u16 VS[64 * 256];    // 32 KB, 16B-chunk c stored at c^(row&31)

  const int tid = threadIdx.x;
  const int wave = tid >> 6, lane = tid & 63;
  const int l32 = lane & 31, hi = lane >> 5;

  // ---- stage K + V (global_load_lds, pre-swizzled source) ----
  {
    const int c8 = lane & 7, r8 = lane >> 3;
    const u16* kbase = Kg + (size_t)(b * LYK) * BD + h * 64 + ((c8 ^ r8) << 3);
#pragma unroll
    for (int j = 0; j < 8; ++j) {
      const int blk = wave * 8 + j;
      gl_lds16(kbase + (size_t)(blk * 8 + r8) * BD, KS + blk * 512);
    }
    const int c32 = lane & 31, r2 = lane >> 5;
#pragma unroll
    for (int j = 0; j < 8; ++j) {
      const int blk = wave * 8 + j;
      const int r = blk * 2 + r2;
      gl_lds16(VT + (size_t)(b * BD + h * 64 + r) * LYK + ((c32 ^ (r & 31)) << 3),
               VS + blk * 512);
    }
  }
  __syncthreads();

  const int qw = q0 + wave * 32;
  if (qw >= qend) return;

  // Q B-fragments: col=query=l32, k = kk*16 + hi*8 + i
  int qrow = qw + l32;
  if (qrow > qend - 1) qrow = qend - 1;
  const u16* qp = Q + (size_t)qrow * BD + h * 64 + hi * 8;
  s16x8 bq[4];
#pragma unroll
  for (int kk = 0; kk < 4; ++kk) bq[kk] = *(const s16x8*)(qp + kk * 16);

  // S^T = K Q^T : D[key][query]; lane: query=l32, keys (r&3)+8*(r>>2)+4*hi
  f32x16 sacc[8];
#pragma unroll
  for (int kt = 0; kt < 8; ++kt)
#pragma unroll
    for (int r = 0; r < 16; ++r) sacc[kt][r] = 0.f;
#pragma unroll
  for (int kt = 0; kt < 8; ++kt) {
    const int krow = kt * 32 + l32;
    const u16* kp = &KS[krow * 64];
#pragma unroll
    for (int kk = 0; kk < 4; ++kk) {
      const int c = kk * 2 + hi;
      const s16x8 ka = *(const s16x8*)(kp + ((c ^ (krow & 7)) << 3));
      sacc[kt] = mfma32(ka, bq[kk], sacc[kt]);
    }
  }

  // softmax max for query l32: in-lane over 128 + one shfl
  f32x16 m16 = sacc[0];
#pragma unroll
  for (int kt = 1; kt < 8; ++kt)
#pragma unroll
    for (int r = 0; r < 16; ++r) m16[r] = fmaxf(m16[r], sacc[kt][r]);
#pragma unroll
  for (int r = 0; r < 8; ++r) m16[r] = fmaxf(m16[r], m16[r + 8]);
#pragma unroll
  for (int r = 0; r < 4; ++r) m16[r] = fmaxf(m16[r], m16[r + 4]);
  float mx = fmaxf(fmaxf(m16[0], m16[1]), fmaxf(m16[2], m16[3]));
  mx = fmaxf(mx, __shfl_xor(mx, 32));
  const float c1 = 0.18033688011112042f;  // 0.125 * log2(e)
  const float mc = -mx * c1;

  // exp2 in place + sum
  f32x16 ssum;
#pragma unroll
  for (int r = 0; r < 16; ++r) ssum[r] = 0.f;
#pragma unroll
  for (int kt = 0; kt < 8; ++kt)
#pragma unroll
    for (int r = 0; r < 16; ++r) {
      const float p = __builtin_exp2f(fmaf(sacc[kt][r], c1, mc));
      sacc[kt][r] = p;
      ssum[r] += p;
    }
#pragma unroll
  for (int r = 0; r < 8; ++r) ssum[r] += ssum[r + 8];
#pragma unroll
  for (int r = 0; r < 4; ++r) ssum[r] += ssum[r + 4];
  float sum = (ssum[0] + ssum[1]) + (ssum[2] + ssum[3]);
  sum += __shfl_xor(sum, 32);
  const float inv = 1.f / sum;

  // O = P V : per key-tile, pack normalized P pairs (all of a lane's P
  // belong to query l32 -> scale by own inv), 2 swaps per 16-key chunk
  // build A-frags; B-frags from swizzled VS.
  f32x16 oacc0, oacc1;
#pragma unroll
  for (int r = 0; r < 16; ++r) { oacc0[r] = 0.f; oacc1[r] = 0.f; }
#pragma unroll
  for (int kt = 0; kt < 8; ++kt) {
    uint32_t pk[8];
#pragma unroll
    for (int j = 0; j < 8; ++j)
      pk[j] = cvtpk(sacc[kt][2 * j] * inv, sacc[kt][2 * j + 1] * inv);
    // kc=0: keys 0..15 of tile; kc=1: keys 16..31
    asm("v_permlane32_swap_b32 %0, %1" : "+v"(pk[0]), "+v"(pk[2]));
    asm("v_permlane32_swap_b32 %0, %1" : "+v"(pk[1]), "+v"(pk[3]));
    asm("v_permlane32_swap_b32 %0, %1" : "+v"(pk[4]), "+v"(pk[6]));
    asm("v_permlane32_swap_b32 %0, %1" : "+v"(pk[5]), "+v"(pk[7]));
#pragma unroll
    for (int kc = 0; kc < 2; ++kc) {
      i32x4 aw;
      aw[0] = (int)pk[4 * kc];     aw[1] = (int)pk[4 * kc + 1];
      aw[2] = (int)pk[4 * kc + 2]; aw[3] = (int)pk[4 * kc + 3];
      const s16x8 ap = __builtin_bit_cast(s16x8, aw);
      const int c = kt * 4 + kc * 2 + hi;
#pragma unroll
      for (int dt = 0; dt < 2; ++dt) {
        const int drow = dt * 32 + l32;
        const s16x8 bv = *(const s16x8*)&VS[drow * 256 + ((c ^ (drow & 31)) << 3)];
        if (dt == 0) oacc0 = mfma32(ap, bv, oacc0);
        else         oacc1 = mfma32(ap, bv, oacc1);
      }
    }
  }

  // epilogue: D[query][d]: d = dt*32 + l32, query = (r&3)+8*(r>>2)+4*hi
#pragma unroll
  for (int r = 0; r < 16; ++r) {
    const int qv = (r & 3) + 8 * (r >> 2) + 4 * hi;
    const int q = qw + qv;
    if (q < qend) {
      u16* op = O + (size_t)q * BD + h * 64 + l32;
      op[0]  = f2bf(oacc0[r]);
      op[32] = f2bf(oacc1[r]);
    }
  }
}

extern "C" void kernel_launch(void* const* d_in, const int* in_sizes, int n_in,
                              void* d_out, int out_size, void* d_ws, size_t ws_size,
                              hipStream_t stream) {
  const float* F    = (const float*)d_in[0];
  const float* yIn  = (const float*)d_in[1];
  const float* ln_g = (const float*)d_in[2];
  const float* ln_b = (const float*)d_in[3];
  const float* Wq   = (const float*)d_in[4];
  const float* Wk   = (const float*)d_in[5];
  const float* Wv   = (const float*)d_in[6];
  const float* bq   = (const float*)d_in[7];
  const float* bk   = (const float*)d_in[8];
  const float* bv   = (const float*)d_in[9];
  const float* Wo   = (const float*)d_in[10];
  const float* bo   = (const float*)d_in[11];
  const float* W1   = (const float*)d_in[12];
  const float* b1   = (const float*)d_in[13];
  const float* W2   = (const float*)d_in[14];
  const float* b2   = (const float*)d_in[15];
  const int* bids   = (const int*)d_in[16];

  char* ws = (char*)d_ws;
  size_t cur = 0;
  auto alloc = [&](size_t bytes) {
    void* p = ws + cur;
    cur += (bytes + 255) & ~(size_t)255;
    return p;
  };

  int* off   = (int*)alloc(68);
  u16* wq_b  = (u16*)alloc((size_t)262144 * 2);
  u16* wkv_b = (u16*)alloc((size_t)524288 * 2);   // [Wk; Wv] stacked, 1024x512
  u16* wo_b  = (u16*)alloc((size_t)262144 * 2);
  u16* w2_b  = (u16*)alloc((size_t)262144 * 2);
  u16* w1_b  = (u16*)alloc((size_t)393216 * 2);
  u16* y_b   = (u16*)alloc((size_t)3145728 * 2);
  u16* U     = (u16*)alloc((size_t)4096 * BD * 2);
  u16* ym    = (u16*)alloc((size_t)4096 * BD * 2);
  u16* Kb    = (u16*)alloc((size_t)4096 * BD * 2);
  u16* VT    = (u16*)alloc((size_t)NB * BD * LYK * 2);  // [b][dh_full][key]
  u16* xn    = (u16*)alloc((size_t)NTOK * BD * 2);
  u16* Qb    = (u16*)alloc((size_t)NTOK * BD * 2);
  u16* Ob    = (u16*)alloc((size_t)NTOK * BD * 2);
  u16* Zb    = (u16*)alloc((size_t)NTOK * BD * 2);

  prep<<<10561, 256, 0, stream>>>(Wq, Wk, Wv, Wo, W2, W1, yIn, F, ln_g, ln_b, bids,
                                  wq_b, wkv_b, wo_b, w2_b, w1_b, y_b, xn, off);

  // image-feature MLP (M = 4096)
  gemm64<1><<<dim3(64, 4), 256, 0, stream>>>(y_b, w1_b, b1, U, IMGD);
  gemm64<0><<<dim3(64, 4), 256, 0, stream>>>(U, w2_b, b2, ym, BD);
  // fused K/V projection, N=1024; V written transposed into VT
  gemm128<3, 0><<<dim3(32, 8), 256, 0, stream>>>(ym, wkv_b, bk, Kb, nullptr, VT, bv, BD);
  // Q projection (M = 32768), XCD-swizzled 1-D grid
  gemm128<0, 1><<<1024, 256, 0, stream>>>(xn, wq_b, bq, Qb, nullptr, nullptr, nullptr, BD);
  // cross-attention: one block per (128-query chunk, head, batch)
  attn_k<<<dim3(18, 8, NB), 256, 0, stream>>>(Qb, Kb, VT, off, Ob);
  // output projection + residual, XCD-swizzled
  gemm128<2, 1><<<1024, 256, 0, stream>>>(Ob, wo_b, bo, Zb, xn, nullptr, nullptr, BD);
  ln_bf16_f32<<<NTOK / 4, 256, 0, stream>>>(Zb, ln_g, ln_b, (float*)d_out);
}